// Round 1
// baseline (202.808 us; speedup 1.0000x reference)
//
#include <hip/hip_runtime.h>

#define S_    2048
#define N_    16
#define OBS_  8
#define PRED_ 12
#define B_    (S_*N_)

typedef __attribute__((ext_vector_type(8))) short short8;
typedef __attribute__((ext_vector_type(4))) float floatx4;
typedef __attribute__((ext_vector_type(4))) unsigned uintx4;
typedef unsigned short ushort_t;

__device__ __forceinline__ float sigmf(float x) { return __builtin_amdgcn_rcpf(1.0f + __expf(-x)); }
__device__ __forceinline__ float tanhx(float x) { return fmaf(-2.0f, __builtin_amdgcn_rcpf(1.0f + __expf(2.0f*x)), 1.0f); }
// f32 -> bf16 round-half-up: bits+0x8000, truncate. <=0.5 ulp like RNE (ties differ only).
__device__ __forceinline__ unsigned bfhi(float f) {
  return __builtin_bit_cast(unsigned, f) + 0x8000u;
}
__device__ __forceinline__ unsigned pack2bf(float lo, float hi) {
  return __builtin_amdgcn_perm(bfhi(hi), bfhi(lo), 0x07060302);  // [hi.b3,hi.b2,lo.b3,lo.b2]
}
__device__ __forceinline__ ushort_t f2bf1(float f) { return (ushort_t)(bfhi(f) >> 16); }

// R14: redundant-gate restructure. Each wave computes ALL 4 gate MFMAs and the
// full elementwise for every (agent,unit); LSTM state (c,h,e) is wave-private:
// lane (lq,lc) owns agent lc, units lq*4..+3, identical across waves (same
// inputs -> bitwise-identical values, so redundancy is race-free by design).
// Cross-wave traffic shrinks to {ctx, prev, pos}, double-buffered by t&1.
// Barriers: 65 -> 13 (1 init + 12 decoder E). Hazard ledger:
//  - e_w/h_w: per-wave buffers, same-wave cross-lane LDS write->read ordered by
//    lgkmcnt (R12/R13 precedent with ctx_s/h_s). No other wave ever touches them.
//  - re_s: wave-local already (wave w writes rows 4w..4w+3 in phase 3, reads the
//    same rows in phase 4) — old barrier C was only for hb_s, which is gone.
//  - h_s/ctx_s: same-wave (wave w writes agents 4w..4w+3; phase-5 reader thread
//    (i,k) is wave i>>2). Single-buffered, program-order safe.
//  - ctx_bf/prev_bf/pos_s: read buf[p], written buf[p^1], barrier E each step ->
//    max skew <1 step, no WAR.
// Spill tripwire: FETCH/WRITE ~3.9/9.2 MB; VGPR budget ~120 under (256,4) cap.
extern "C" __global__ __launch_bounds__(256, 4) void traj_ar_kernel(
    const float* __restrict__ traj_rel, const float* __restrict__ obs_pos,
    const int*  __restrict__ nei,       const float* __restrict__ noise,
    const float* __restrict__ eeW, const float* __restrict__ eeb,
    const float* __restrict__ eWi, const float* __restrict__ eWh, const float* __restrict__ eb,
    const float* __restrict__ diW, const float* __restrict__ dib,
    const float* __restrict__ dWi, const float* __restrict__ dWh, const float* __restrict__ db,
    const float* __restrict__ prW, const float* __restrict__ prb,
    const float* __restrict__ mW,  const float* __restrict__ mb,
    const float* __restrict__ oW,  const float* __restrict__ ob,
    float* __restrict__ out)
{
  __shared__ __align__(16) float sW_pr[32];
  __shared__ __align__(16) float sb_pr[16];
  __shared__ __align__(16) float sW_o[64];
  __shared__ __align__(16) float sb_o[4];
  // same-wave f32 state for phase 5
  __shared__ __align__(16) float h_s[256];
  __shared__ __align__(16) float ctx_s[256];
  // wave-private bf16 activations, [wave][agent][unit], row stride 24 ushorts
  __shared__ __align__(16) ushort_t e_w[4*384];
  __shared__ __align__(16) ushort_t h_w[4*384];
  // cross-wave, double-buffered by t&1
  __shared__ __align__(16) ushort_t ctx_bf[2][384];
  __shared__ __align__(16) float pos_s[2][32];
  __shared__ __align__(16) ushort_t prev_bf[2][32];
  // pool embeddings bf16: [i][j] j-stride 24 ushorts, i-stride 392 (784B); wave-local rows
  __shared__ __align__(16) ushort_t re_s[16*392];
  __shared__            unsigned sm_s[16];

  const int tid = threadIdx.x;
  const int s = blockIdx.x;
  const int i = tid >> 4;
  const int k = tid & 15;
  const int bi = s*N_ + i;
  const int lq = (tid & 63) >> 4;       // quad within wave
  const int lc = tid & 15;              // col within wave (== k)
  const int w  = tid >> 6;              // wave index
  const int l  = tid & 63;
  const int u0 = lq*4;                  // this lane's unit base

  // ---- stage small weights + init cross-wave state ----
  if (tid < 32) sW_pr[tid] = prW[tid];
  if (tid < 16) sb_pr[tid] = prb[tid];
  if (tid < 64) sW_o[tid] = oW[tid];
  if (tid < 4)  sb_o[tid] = ob[tid];
  if (tid < 192) ((unsigned*)ctx_bf)[tid] = 0;   // ctx_bf[0] fully zeroed (R13 lesson)
  {
    // own wave's h buffer = h0 = 0 (wave-private: no barrier needed)
    unsigned* hz = (unsigned*)&h_w[w*384];
    hz[l] = 0; hz[64+l] = 0; hz[128+l] = 0;
  }

  if (k < 2) {
    float pv = traj_rel[((OBS_-1)*B_ + bi)*2 + k];
    prev_bf[0][i*2+k] = f2bf1(pv);                        // out init = traj_rel[OBS-1]
    pos_s[0][i*2+k]  = obs_pos[((OBS_-1)*B_ + bi)*2 + k]; // pos init = obs_traj_pos[-1]
  }

  // pool-MLP B-fragment (32x16 bf16 weights)
  short8 bfrag;
  {
    uintx4 bw;
    #pragma unroll
    for (int p = 0; p < 4; ++p)
      bw[p] = pack2bf(mW[(8*lq + 2*p)*16 + lc], mW[(8*lq + 2*p + 1)*16 + lc]);
    bfrag = __builtin_bit_cast(short8, bw);
  }
  const float bm = mb[lc];

  // encoder embed weights for this lane's 4 units
  float ew0[4], ew1[4], ebv[4];
  #pragma unroll
  for (int r = 0; r < 4; ++r) {
    ew0[r] = eeW[u0+r]; ew1[r] = eeW[16+u0+r]; ebv[r] = eeb[u0+r];
  }

  const int row0 = (lq & 1) * 8;

  // gate A-fragment for gate g (A[row=lc][k] = W[k][g*16+lc]) + bias C by D-row unit
  #define LOAD_GATE_FRAG(A, C, Wi_, Wh_, bias_, g) {                                   \
    const float* gsrc_ = (lq & 2) ? (Wh_) : (Wi_);                                     \
    uintx4 aw_;                                                                        \
    aw_[0] = pack2bf(gsrc_[(row0+0)*64 + (g)*16 + lc], gsrc_[(row0+1)*64 + (g)*16 + lc]); \
    aw_[1] = pack2bf(gsrc_[(row0+2)*64 + (g)*16 + lc], gsrc_[(row0+3)*64 + (g)*16 + lc]); \
    aw_[2] = pack2bf(gsrc_[(row0+4)*64 + (g)*16 + lc], gsrc_[(row0+5)*64 + (g)*16 + lc]); \
    aw_[3] = pack2bf(gsrc_[(row0+6)*64 + (g)*16 + lc], gsrc_[(row0+7)*64 + (g)*16 + lc]); \
    (A) = __builtin_bit_cast(short8, aw_);                                             \
    (C)[0] = (bias_)[(g)*16 + u0 + 0]; (C)[1] = (bias_)[(g)*16 + u0 + 1];              \
    (C)[2] = (bias_)[(g)*16 + u0 + 2]; (C)[3] = (bias_)[(g)*16 + u0 + 3];              \
  }

  // encoder gate A-frags for ALL 4 gates (redundant-gate scheme)
  short8 eA0, eA1, eA2, eA3; floatx4 eC0, eC1, eC2, eC3;
  LOAD_GATE_FRAG(eA0, eC0, eWi, eWh, eb, 0);
  LOAD_GATE_FRAG(eA1, eC1, eWi, eWh, eb, 1);
  LOAD_GATE_FRAG(eA2, eC2, eWi, eWh, eb, 2);
  LOAD_GATE_FRAG(eA3, eC3, eWi, eWh, eb, 3);

  // time-invariant neighbor mask -> per-agent bitmask in LDS
  unsigned long long bal = __ballot(nei[bi*N_ + k] > 0);
  if (k == 0) sm_s[i] = (unsigned)((bal >> (16*(i & 3))) & 0xFFFFull);

  __syncthreads();  // ONLY init barrier: weights/sm/pos/prev/ctx_bf[0] visible

  ushort_t* ewp = &e_w[w*384];
  ushort_t* hwp = &h_w[w*384];

  #define LSTM_EW(r, hv) {                                                            \
    float ig = sigmf(dI[r]), fg = sigmf(dF[r]), gv = tanhx(dG[r]), og = sigmf(dO[r]); \
    c4[r] = fg*c4[r] + ig*gv;                                                         \
    hv = og * tanhx(c4[r]);                                                           \
  }

  // ---- encoder: 8 LSTM steps, ZERO barriers ----
  floatx4 c4 = {0.0f, 0.0f, 0.0f, 0.0f};
  const float2* xr2 = (const float2*)traj_rel;
  for (int t = 0; t < OBS_; ++t) {
    // e[lc][u0..+3] = relu(x @ eeW + b), computed redundantly per wave
    float2 x = xr2[t*B_ + s*N_ + lc];
    float e0 = fmaxf(fmaf(x.y, ew1[0], fmaf(x.x, ew0[0], ebv[0])), 0.0f);
    float e1 = fmaxf(fmaf(x.y, ew1[1], fmaf(x.x, ew0[1], ebv[1])), 0.0f);
    float e2 = fmaxf(fmaf(x.y, ew1[2], fmaf(x.x, ew0[2], ebv[2])), 0.0f);
    float e3 = fmaxf(fmaf(x.y, ew1[3], fmaf(x.x, ew0[3], ebv[3])), 0.0f);
    uint2 ep; ep.x = pack2bf(e0, e1); ep.y = pack2bf(e2, e3);
    *(uint2*)&ewp[lc*24 + u0] = ep;                  // wave-private, same-wave read below
    const ushort_t* bp = (lq < 2) ? &ewp[lc*24 + (lq&1)*8] : &hwp[lc*24 + (lq&1)*8];
    short8 bfr = *(const short8*)bp;
    floatx4 dI = __builtin_amdgcn_mfma_f32_16x16x32_bf16(eA0, bfr, eC0, 0, 0, 0);
    floatx4 dF = __builtin_amdgcn_mfma_f32_16x16x32_bf16(eA1, bfr, eC1, 0, 0, 0);
    floatx4 dG = __builtin_amdgcn_mfma_f32_16x16x32_bf16(eA2, bfr, eC2, 0, 0, 0);
    floatx4 dO = __builtin_amdgcn_mfma_f32_16x16x32_bf16(eA3, bfr, eC3, 0, 0, 0);
    float h40, h41, h42, h43;
    LSTM_EW(0, h40); LSTM_EW(1, h41); LSTM_EW(2, h42); LSTM_EW(3, h43);
    uint2 hp2; hp2.x = pack2bf(h40, h41); hp2.y = pack2bf(h42, h43);
    *(uint2*)&hwp[lc*24 + u0] = hp2;                 // wave-private
  }

  // decoder gate A-frags (all 4 gates; separate live range from encoder's)
  short8 dA0, dA1, dA2, dA3; floatx4 dC0, dC1, dC2, dC3;
  LOAD_GATE_FRAG(dA0, dC0, dWi, dWh, db, 0);
  LOAD_GATE_FRAG(dA1, dC1, dWi, dWh, db, 1);
  LOAD_GATE_FRAG(dA2, dC2, dWi, dWh, db, 2);
  LOAD_GATE_FRAG(dA3, dC3, dWi, dWh, db, 3);

  // dec-in A-fragment: kk 0..15 = ctx rows, 16,17 = prev rows, 18..31 zero-pad
  short8 diA; floatx4 diC;
  {
    uintx4 aw; aw[0]=0; aw[1]=0; aw[2]=0; aw[3]=0;
    if (lq < 2) {
      const int r0 = lq*8;
      #pragma unroll
      for (int p = 0; p < 4; ++p)
        aw[p] = pack2bf(diW[(r0+2*p)*16 + lc], diW[(r0+2*p+1)*16 + lc]);
    } else if (lq == 2) {
      aw[0] = pack2bf(diW[16*16 + lc], diW[17*16 + lc]);
    }
    diA = __builtin_bit_cast(short8, aw);
    #pragma unroll
    for (int r = 0; r < 4; ++r) diC[r] = dib[u0 + r];
  }

  // pool C-operands with mask baked in (time-invariant; sm_s rows 4w..4w+3 are same-wave)
  floatx4 cm0, cm1, cm2, cm3;
  {
    #pragma unroll
    for (int tt = 0; tt < 4; ++tt) {
      const unsigned mi = sm_s[4*w + tt];
      floatx4 cf;
      #pragma unroll
      for (int r = 0; r < 4; ++r)
        cf[r] = ((mi >> (lq*4 + r)) & 1u) ? bm : -1e9f;
      if (tt==0) cm0=cf; else if (tt==1) cm1=cf; else if (tt==2) cm2=cf; else cm3=cf;
    }
  }

  // ---- decoder: 12 autoregressive steps, ONE barrier/step ----
  c4 = (floatx4){0.0f, 0.0f, 0.0f, 0.0f};
  const int MU_OFF = PRED_*B_*2;
  const int SD_OFF = 2*PRED_*B_*2;
  for (int t = 0; t < PRED_; ++t) {
    const int p = t & 1;
    // early noise load: consumed in phase 5
    const float nz = noise[(t*B_ + bi)*2 + (k & 1)];
    // phase 1: e = relu([ctx|prev] @ dec_in_W + b) via MFMA; every wave writes its
    // OWN e buffer (reads buf[p], written pre-E of previous step).
    {
      short8 cv = *(const short8*)&ctx_bf[p][lc*24 + (lq&1)*8];
      uintx4 pz; pz[0] = *(const unsigned*)&prev_bf[p][lc*2]; pz[1]=0; pz[2]=0; pz[3]=0;
      short8 pv = __builtin_bit_cast(short8, pz);
      short8 zz = {0,0,0,0,0,0,0,0};
      short8 bf1 = (lq < 2) ? cv : ((lq == 2) ? pv : zz);
      floatx4 d = __builtin_amdgcn_mfma_f32_16x16x32_bf16(diA, bf1, diC, 0, 0, 0);
      uint2 ep;
      ep.x = pack2bf(fmaxf(d[0],0.0f), fmaxf(d[1],0.0f));
      ep.y = pack2bf(fmaxf(d[2],0.0f), fmaxf(d[3],0.0f));
      *(uint2*)&ewp[lc*24 + u0] = ep;
    }
    // phase 2: all 4 gate MFMAs + redundant elementwise; h stays wave-private.
    {
      const ushort_t* bp = (lq < 2) ? &ewp[lc*24 + (lq&1)*8] : &hwp[lc*24 + (lq&1)*8];
      short8 bfr = *(const short8*)bp;
      floatx4 dI = __builtin_amdgcn_mfma_f32_16x16x32_bf16(dA0, bfr, dC0, 0, 0, 0);
      floatx4 dF = __builtin_amdgcn_mfma_f32_16x16x32_bf16(dA1, bfr, dC1, 0, 0, 0);
      floatx4 dG = __builtin_amdgcn_mfma_f32_16x16x32_bf16(dA2, bfr, dC2, 0, 0, 0);
      floatx4 dO = __builtin_amdgcn_mfma_f32_16x16x32_bf16(dA3, bfr, dC3, 0, 0, 0);
      float h40, h41, h42, h43;
      LSTM_EW(0, h40); LSTM_EW(1, h41); LSTM_EW(2, h42); LSTM_EW(3, h43);
      uint2 hp2; hp2.x = pack2bf(h40, h41); hp2.y = pack2bf(h42, h43);
      *(uint2*)&hwp[lc*24 + u0] = hp2;               // wave-private (pool + next gates)
      if ((lc >> 2) == w) {                          // f32 h for phase 5, same-wave rows
        floatx4 hv; hv[0]=h40; hv[1]=h41; hv[2]=h42; hv[3]=h43;
        *(floatx4*)&h_s[lc*16 + u0] = hv;
      }
    }
    // phase 3: re[i][j=k][:] = relu(rel @ prW + b); rows i are wave-local for phase 4
    {
      float rx = pos_s[p][i*2+0] - pos_s[p][k*2+0];
      float ry = pos_s[p][i*2+1] - pos_s[p][k*2+1];
      uintx4 v0, v1;
      #pragma unroll
      for (int m = 0; m < 4; ++m) {
        float a0 = fmaxf(fmaf(ry, sW_pr[16+2*m], fmaf(rx, sW_pr[2*m],   sb_pr[2*m])),   0.0f);
        float a1 = fmaxf(fmaf(ry, sW_pr[17+2*m], fmaf(rx, sW_pr[2*m+1], sb_pr[2*m+1])), 0.0f);
        float b0 = fmaxf(fmaf(ry, sW_pr[24+2*m], fmaf(rx, sW_pr[8+2*m], sb_pr[8+2*m])), 0.0f);
        float b1 = fmaxf(fmaf(ry, sW_pr[25+2*m], fmaf(rx, sW_pr[9+2*m], sb_pr[9+2*m])), 0.0f);
        v0[m] = pack2bf(a0, a1);
        v1[m] = pack2bf(b0, b1);
      }
      uintx4* rp = (uintx4*)&re_s[i*392 + k*24];
      rp[0] = v0;
      rp[1] = v1;
    }
    // phase 4: masked max-pool via MFMA; ctx f32 same-wave + ctx bf16 -> buf[p^1]
    {
      const ushort_t* hbp = &hwp[lc*24 + (lq-2)*8];
      #pragma unroll
      for (int tt = 0; tt < 4; ++tt) {
        const int it = 4*w + tt;
        const ushort_t* rep = &re_s[it*392 + lc*24 + lq*8];
        const ushort_t* ap = (lq < 2) ? rep : hbp;
        short8 a = *(const short8*)ap;
        const floatx4 cmv = (tt==0)?cm0:(tt==1)?cm1:(tt==2)?cm2:cm3;
        floatx4 d = __builtin_amdgcn_mfma_f32_16x16x32_bf16(a, bfrag, cmv, 0, 0, 0);
        float pm = fmaxf(fmaxf(d[0], d[1]), fmaxf(d[2], d[3]));
        pm = fmaxf(pm, __shfl_xor(pm, 16, 64));
        pm = fmaxf(pm, __shfl_xor(pm, 32, 64));
        if (lq == tt) {
          float cvv = fmaxf(pm, 0.0f);
          ctx_s[it*16 + lc] = cvv;                   // same-wave consumer (phase 5)
          ctx_bf[p^1][it*24 + lc] = f2bf1(cvv);      // cross-wave, covered by E
        }
      }
    }
    // phase 5: o4 = (h+ctx)@out_W + b; outputs; advance pos/prev into buf[p^1]
    {
      float o4v = 0.0f;
      if (k < 4) {
        const float* hp = &h_s[i*16];
        const float* cx = &ctx_s[i*16];
        float acc = sb_o[k];
        #pragma unroll
        for (int m = 0; m < 16; ++m) acc = fmaf(hp[m]+cx[m], sW_o[m*4+k], acc);
        o4v = acc;
      }
      float sc = __shfl_down(o4v, 2, 64);   // lane k<2 grabs o4[2+k]
      if (k < 2) {
        float mu = o4v;
        float scale = fminf(fmaxf(sc, -9.0f), 4.0f);
        float sd = __expf(scale);
        float pr = fmaf(sd, nz, mu);
        int o = (t*B_ + bi)*2 + k;
        out[o]          = pr;
        out[MU_OFF + o] = mu;
        out[SD_OFF + o] = sd;
        pos_s[p^1][i*2+k] = pos_s[p][i*2+k] + pr;
        prev_bf[p^1][i*2+k] = f2bf1(pr);
      }
    }
    __syncthreads(); // E: ctx_bf/prev_bf/pos_s buf[p^1] cross-wave for next step
  }
  #undef LSTM_EW
  #undef LOAD_GATE_FRAG
}

extern "C" void kernel_launch(void* const* d_in, const int* in_sizes, int n_in,
                              void* d_out, int out_size, void* d_ws, size_t ws_size,
                              hipStream_t stream) {
  (void)in_sizes; (void)n_in; (void)d_ws; (void)ws_size; (void)out_size;
  traj_ar_kernel<<<dim3(S_), dim3(256), 0, stream>>>(
      (const float*)d_in[0],  (const float*)d_in[1],  (const int*)d_in[2],   (const float*)d_in[3],
      (const float*)d_in[4],  (const float*)d_in[5],  (const float*)d_in[6], (const float*)d_in[7],
      (const float*)d_in[8],  (const float*)d_in[9],  (const float*)d_in[10],(const float*)d_in[11],
      (const float*)d_in[12], (const float*)d_in[13], (const float*)d_in[14],(const float*)d_in[15],
      (const float*)d_in[16], (const float*)d_in[17], (const float*)d_in[18],(const float*)d_in[19],
      (float*)d_out);
}

// Round 2
// 165.225 us; speedup vs baseline: 1.2275x; 1.2275x over previous
//
#include <hip/hip_runtime.h>

#define S_    2048
#define N_    16
#define OBS_  8
#define PRED_ 12
#define B_    (S_*N_)
#define SCN_  2     // scenes (waves) per block

typedef __attribute__((ext_vector_type(8))) short short8;
typedef __attribute__((ext_vector_type(4))) float floatx4;
typedef __attribute__((ext_vector_type(4))) unsigned uintx4;
typedef unsigned short ushort_t;

__device__ __forceinline__ float sigmf(float x) { return __builtin_amdgcn_rcpf(1.0f + __expf(-x)); }
__device__ __forceinline__ float tanhx(float x) { return fmaf(-2.0f, __builtin_amdgcn_rcpf(1.0f + __expf(2.0f*x)), 1.0f); }
// f32 -> bf16 round-half-up: bits+0x8000, truncate. <=0.5 ulp like RNE (ties differ only).
__device__ __forceinline__ unsigned bfhi(float f) {
  return __builtin_bit_cast(unsigned, f) + 0x8000u;
}
__device__ __forceinline__ unsigned pack2bf(float lo, float hi) {
  return __builtin_amdgcn_perm(bfhi(hi), bfhi(lo), 0x07060302);  // [hi.b3,hi.b2,lo.b3,lo.b2]
}
__device__ __forceinline__ ushort_t f2bf1(float f) { return (ushort_t)(bfhi(f) >> 16); }

// R15: wave-per-scene, ZERO steady-state barriers. R14 post-mortem: 4x redundant
// elementwise doubled VALU cycles (VALUBusy 46->65% while dur 90->124us) — wrong
// trade. This version keeps R13's total arithmetic (each (agent,unit) computed
// once) but makes each WAVE own a full scene: lane (lq,lc) = agent lc, units
// lq*4..+3; all 21 MFMAs/step + elementwise + pool on one wave. All hand-offs
// are same-wave in-order LDS (R12/R13/R14-verified mechanism). Barriers: 1
// (init, for shared sW_* staging only). 2 scenes per 128-thr block; LDS 34.8KB
// -> 4 blocks/CU; grid 1024 = exactly 4/CU = 8 waves/CU. launch_bounds(128,2)
// caps VGPR at 256 so cm[16] (64 VGPR of baked pool-mask C operands) stays in
// registers; all cm/xs accesses are in fully-unrolled loops (rule #20).
// Spill tripwire: WRITE >> 9.5MB or VGPR >= 240 -> cm spilled, fall back to
// per-tt recompute from sm_s.
extern "C" __global__ __launch_bounds__(128, 2) void traj_ar_kernel(
    const float* __restrict__ traj_rel, const float* __restrict__ obs_pos,
    const int*  __restrict__ nei,       const float* __restrict__ noise,
    const float* __restrict__ eeW, const float* __restrict__ eeb,
    const float* __restrict__ eWi, const float* __restrict__ eWh, const float* __restrict__ eb,
    const float* __restrict__ diW, const float* __restrict__ dib,
    const float* __restrict__ dWi, const float* __restrict__ dWh, const float* __restrict__ db,
    const float* __restrict__ prW, const float* __restrict__ prb,
    const float* __restrict__ mW,  const float* __restrict__ mb,
    const float* __restrict__ oW,  const float* __restrict__ ob,
    float* __restrict__ out)
{
  __shared__ __align__(16) float sW_pr[32];
  __shared__ __align__(16) float sb_pr[16];
  __shared__ __align__(16) float sW_o[64];
  __shared__ __align__(16) float sb_o[4];
  // per-scene (wave-private) state
  __shared__ __align__(16) float h_s[SCN_][256];       // f32 h, phase-5 input
  __shared__ __align__(16) float ctx_s[SCN_][256];     // f32 ctx, phase-5 input
  __shared__ __align__(16) ushort_t e_w[SCN_][384];    // bf16 e, stride 24/agent
  __shared__ __align__(16) ushort_t h_w[SCN_][384];    // bf16 h
  __shared__ __align__(16) ushort_t ctx_bf[SCN_][384]; // bf16 ctx, phase-1 B input
  __shared__ __align__(16) float pos_s[SCN_][32];
  __shared__ __align__(16) ushort_t prev_bf[SCN_][32];
  // pool embeddings bf16: [i][j] j-stride 24 ushorts, i-stride 392 (784B)
  __shared__ __align__(16) ushort_t re_s[SCN_][16*392];
  __shared__            unsigned sm_s[SCN_][16];

  const int tid = threadIdx.x;
  const int w  = tid >> 6;              // wave index == scene-within-block
  const int l  = tid & 63;
  const int lq = l >> 4;                // quad within wave
  const int lc = l & 15;                // col within wave (agent / unit-col)
  const int u0 = lq*4;                  // this lane's unit base
  const int s  = blockIdx.x*SCN_ + w;   // this wave's scene

  // ---- stage shared small weights (wave 0) + per-wave scene init ----
  if (tid < 32) sW_pr[tid] = prW[tid];
  if (tid < 16) sb_pr[tid] = prb[tid];
  if (tid < 64) sW_o[tid] = oW[tid];
  if (tid < 4)  sb_o[tid] = ob[tid];
  {
    // own wave's h0 = 0 and ctx0 = 0 (FULL 192 uints each — R13 lesson)
    unsigned* hz = (unsigned*)h_w[w];
    unsigned* cz = (unsigned*)ctx_bf[w];
    hz[l] = 0; hz[64+l] = 0; hz[128+l] = 0;
    cz[l] = 0; cz[64+l] = 0; cz[128+l] = 0;
  }
  if (l < 32) {
    const int a = l >> 1, c = l & 1;
    float pv = traj_rel[((OBS_-1)*B_ + s*N_ + a)*2 + c];
    prev_bf[w][a*2+c] = f2bf1(pv);                          // out init = traj_rel[OBS-1]
    pos_s[w][a*2+c]  = obs_pos[((OBS_-1)*B_ + s*N_ + a)*2 + c];
  }
  // time-invariant neighbor mask -> per-agent bitmask (wave-private)
  {
    const int a = l >> 2, nb = (l & 3)*4;
    const int4 nv = *(const int4*)&nei[(s*N_ + a)*N_ + nb];
    unsigned bits = 0;
    bits |= (nv.x > 0) ? (1u << (nb+0)) : 0u;
    bits |= (nv.y > 0) ? (1u << (nb+1)) : 0u;
    bits |= (nv.z > 0) ? (1u << (nb+2)) : 0u;
    bits |= (nv.w > 0) ? (1u << (nb+3)) : 0u;
    bits |= __shfl_xor(bits, 1, 64);
    bits |= __shfl_xor(bits, 2, 64);
    if ((l & 3) == 0) sm_s[w][a] = bits;
  }

  // pool-MLP B-fragment (32x16 bf16 weights)
  short8 bfrag;
  {
    uintx4 bw;
    #pragma unroll
    for (int p = 0; p < 4; ++p)
      bw[p] = pack2bf(mW[(8*lq + 2*p)*16 + lc], mW[(8*lq + 2*p + 1)*16 + lc]);
    bfrag = __builtin_bit_cast(short8, bw);
  }
  const float bm = mb[lc];

  // encoder embed weights for this lane's 4 units
  float ew0[4], ew1[4], ebv[4];
  #pragma unroll
  for (int r = 0; r < 4; ++r) {
    ew0[r] = eeW[u0+r]; ew1[r] = eeW[16+u0+r]; ebv[r] = eeb[u0+r];
  }

  const int row0 = (lq & 1) * 8;

  // gate A-fragment for gate g (A[row=lc][k] = W[k][g*16+lc]) + bias C by D-row unit
  #define LOAD_GATE_FRAG(A, C, Wi_, Wh_, bias_, g) {                                      \
    const float* gsrc_ = (lq & 2) ? (Wh_) : (Wi_);                                        \
    uintx4 aw_;                                                                           \
    aw_[0] = pack2bf(gsrc_[(row0+0)*64 + (g)*16 + lc], gsrc_[(row0+1)*64 + (g)*16 + lc]); \
    aw_[1] = pack2bf(gsrc_[(row0+2)*64 + (g)*16 + lc], gsrc_[(row0+3)*64 + (g)*16 + lc]); \
    aw_[2] = pack2bf(gsrc_[(row0+4)*64 + (g)*16 + lc], gsrc_[(row0+5)*64 + (g)*16 + lc]); \
    aw_[3] = pack2bf(gsrc_[(row0+6)*64 + (g)*16 + lc], gsrc_[(row0+7)*64 + (g)*16 + lc]); \
    (A) = __builtin_bit_cast(short8, aw_);                                                \
    (C)[0] = (bias_)[(g)*16 + u0 + 0]; (C)[1] = (bias_)[(g)*16 + u0 + 1];                 \
    (C)[2] = (bias_)[(g)*16 + u0 + 2]; (C)[3] = (bias_)[(g)*16 + u0 + 3];                 \
  }

  // encoder gate A-frags, all 4 gates on this wave
  short8 eA0, eA1, eA2, eA3; floatx4 eC0, eC1, eC2, eC3;
  LOAD_GATE_FRAG(eA0, eC0, eWi, eWh, eb, 0);
  LOAD_GATE_FRAG(eA1, eC1, eWi, eWh, eb, 1);
  LOAD_GATE_FRAG(eA2, eC2, eWi, eWh, eb, 2);
  LOAD_GATE_FRAG(eA3, eC3, eWi, eWh, eb, 3);

  __syncthreads();  // ONLY barrier: shared sW_* staged by wave 0, read by all waves

  #define LSTM_EW(r, hv) {                                                            \
    float ig = sigmf(dI[r]), fg = sigmf(dF[r]), gv = tanhx(dG[r]), og = sigmf(dO[r]); \
    c4[r] = fg*c4[r] + ig*gv;                                                         \
    hv = og * tanhx(c4[r]);                                                           \
  }

  // ---- encoder: 8 LSTM steps, zero barriers (all hand-offs same-wave LDS) ----
  floatx4 c4 = {0.0f, 0.0f, 0.0f, 0.0f};
  const float2* xr2 = (const float2*)traj_rel;
  for (int t = 0; t < OBS_; ++t) {
    float2 x = xr2[t*B_ + s*N_ + lc];
    float e0 = fmaxf(fmaf(x.y, ew1[0], fmaf(x.x, ew0[0], ebv[0])), 0.0f);
    float e1 = fmaxf(fmaf(x.y, ew1[1], fmaf(x.x, ew0[1], ebv[1])), 0.0f);
    float e2 = fmaxf(fmaf(x.y, ew1[2], fmaf(x.x, ew0[2], ebv[2])), 0.0f);
    float e3 = fmaxf(fmaf(x.y, ew1[3], fmaf(x.x, ew0[3], ebv[3])), 0.0f);
    uint2 ep; ep.x = pack2bf(e0, e1); ep.y = pack2bf(e2, e3);
    *(uint2*)&e_w[w][lc*24 + u0] = ep;               // same-wave cross-lane hand-off
    const ushort_t* bp = (lq < 2) ? &e_w[w][lc*24 + (lq&1)*8] : &h_w[w][lc*24 + (lq&1)*8];
    short8 bfr = *(const short8*)bp;
    floatx4 dI = __builtin_amdgcn_mfma_f32_16x16x32_bf16(eA0, bfr, eC0, 0, 0, 0);
    floatx4 dF = __builtin_amdgcn_mfma_f32_16x16x32_bf16(eA1, bfr, eC1, 0, 0, 0);
    floatx4 dG = __builtin_amdgcn_mfma_f32_16x16x32_bf16(eA2, bfr, eC2, 0, 0, 0);
    floatx4 dO = __builtin_amdgcn_mfma_f32_16x16x32_bf16(eA3, bfr, eC3, 0, 0, 0);
    float h40, h41, h42, h43;
    LSTM_EW(0, h40); LSTM_EW(1, h41); LSTM_EW(2, h42); LSTM_EW(3, h43);
    uint2 hp2; hp2.x = pack2bf(h40, h41); hp2.y = pack2bf(h42, h43);
    *(uint2*)&h_w[w][lc*24 + u0] = hp2;
  }

  // decoder gate A-frags (separate live range from encoder's)
  short8 dA0, dA1, dA2, dA3; floatx4 dC0, dC1, dC2, dC3;
  LOAD_GATE_FRAG(dA0, dC0, dWi, dWh, db, 0);
  LOAD_GATE_FRAG(dA1, dC1, dWi, dWh, db, 1);
  LOAD_GATE_FRAG(dA2, dC2, dWi, dWh, db, 2);
  LOAD_GATE_FRAG(dA3, dC3, dWi, dWh, db, 3);

  // dec-in A-fragment: kk 0..15 = ctx rows, 16,17 = prev rows, 18..31 zero-pad
  short8 diA; floatx4 diC;
  {
    uintx4 aw; aw[0]=0; aw[1]=0; aw[2]=0; aw[3]=0;
    if (lq < 2) {
      const int r0 = lq*8;
      #pragma unroll
      for (int p = 0; p < 4; ++p)
        aw[p] = pack2bf(diW[(r0+2*p)*16 + lc], diW[(r0+2*p+1)*16 + lc]);
    } else if (lq == 2) {
      aw[0] = pack2bf(diW[16*16 + lc], diW[17*16 + lc]);
    }
    diA = __builtin_bit_cast(short8, aw);
    #pragma unroll
    for (int r = 0; r < 4; ++r) diC[r] = dib[u0 + r];
  }

  // pool C-operands, all 16 target agents, mask baked (time-invariant).
  // 64 VGPR; every access below is constant-indexed via full unroll (rule #20).
  floatx4 cm[16];
  #pragma unroll
  for (int tt = 0; tt < 16; ++tt) {
    const unsigned mi = sm_s[w][tt];
    #pragma unroll
    for (int r = 0; r < 4; ++r)
      cm[tt][r] = ((mi >> (u0 + r)) & 1u) ? bm : -1e9f;
  }

  // ---- decoder: 12 autoregressive steps, ZERO barriers ----
  c4 = (floatx4){0.0f, 0.0f, 0.0f, 0.0f};
  const int MU_OFF = PRED_*B_*2;
  const int SD_OFF = 2*PRED_*B_*2;
  for (int t = 0; t < PRED_; ++t) {
    // early noise load: consumed in phase 5
    const float nz = noise[(t*B_ + s*N_ + lc)*2 + (lq&1)];
    // phase 1: e = relu([ctx|prev] @ dec_in_W + b) via MFMA (reads prev step's
    // ctx_bf/prev_bf — same-wave program order)
    {
      short8 cv = *(const short8*)&ctx_bf[w][lc*24 + (lq&1)*8];
      uintx4 pz; pz[0] = *(const unsigned*)&prev_bf[w][lc*2]; pz[1]=0; pz[2]=0; pz[3]=0;
      short8 pv = __builtin_bit_cast(short8, pz);
      short8 zz = {0,0,0,0,0,0,0,0};
      short8 bf1 = (lq < 2) ? cv : ((lq == 2) ? pv : zz);
      floatx4 d = __builtin_amdgcn_mfma_f32_16x16x32_bf16(diA, bf1, diC, 0, 0, 0);
      uint2 ep;
      ep.x = pack2bf(fmaxf(d[0],0.0f), fmaxf(d[1],0.0f));
      ep.y = pack2bf(fmaxf(d[2],0.0f), fmaxf(d[3],0.0f));
      *(uint2*)&e_w[w][lc*24 + u0] = ep;
    }
    // phase 2: 4 gate MFMAs + elementwise; h -> bf16 (pool/gates) + f32 (phase 5)
    {
      const ushort_t* bp = (lq < 2) ? &e_w[w][lc*24 + (lq&1)*8] : &h_w[w][lc*24 + (lq&1)*8];
      short8 bfr = *(const short8*)bp;
      floatx4 dI = __builtin_amdgcn_mfma_f32_16x16x32_bf16(dA0, bfr, dC0, 0, 0, 0);
      floatx4 dF = __builtin_amdgcn_mfma_f32_16x16x32_bf16(dA1, bfr, dC1, 0, 0, 0);
      floatx4 dG = __builtin_amdgcn_mfma_f32_16x16x32_bf16(dA2, bfr, dC2, 0, 0, 0);
      floatx4 dO = __builtin_amdgcn_mfma_f32_16x16x32_bf16(dA3, bfr, dC3, 0, 0, 0);
      float h40, h41, h42, h43;
      LSTM_EW(0, h40); LSTM_EW(1, h41); LSTM_EW(2, h42); LSTM_EW(3, h43);
      uint2 hp2; hp2.x = pack2bf(h40, h41); hp2.y = pack2bf(h42, h43);
      *(uint2*)&h_w[w][lc*24 + u0] = hp2;
      floatx4 hv4; hv4[0]=h40; hv4[1]=h41; hv4[2]=h42; hv4[3]=h43;
      *(floatx4*)&h_s[w][lc*16 + u0] = hv4;
    }
    // phase 3: re[i=lc][j=u0..u0+3][:] = relu(rel @ prW + b), 4 pairs/lane
    // (reads pos_s BEFORE phase 5 updates it — program order)
    {
      const float pix = pos_s[w][lc*2+0], piy = pos_s[w][lc*2+1];
      #pragma unroll
      for (int jj = 0; jj < 4; ++jj) {
        const int j = u0 + jj;
        const float rx = pix - pos_s[w][j*2+0];
        const float ry = piy - pos_s[w][j*2+1];
        uintx4 v0, v1;
        #pragma unroll
        for (int m = 0; m < 4; ++m) {
          float a0 = fmaxf(fmaf(ry, sW_pr[16+2*m], fmaf(rx, sW_pr[2*m],   sb_pr[2*m])),   0.0f);
          float a1 = fmaxf(fmaf(ry, sW_pr[17+2*m], fmaf(rx, sW_pr[2*m+1], sb_pr[2*m+1])), 0.0f);
          float b0 = fmaxf(fmaf(ry, sW_pr[24+2*m], fmaf(rx, sW_pr[8+2*m], sb_pr[8+2*m])), 0.0f);
          float b1 = fmaxf(fmaf(ry, sW_pr[25+2*m], fmaf(rx, sW_pr[9+2*m], sb_pr[9+2*m])), 0.0f);
          v0[m] = pack2bf(a0, a1);
          v1[m] = pack2bf(b0, b1);
        }
        uintx4* rp = (uintx4*)&re_s[w][lc*392 + j*24];
        rp[0] = v0; rp[1] = v1;
      }
    }
    // phase 4: masked max-pool, all 16 target agents on this wave (16 MFMAs,
    // independent — good ILP); ctx -> f32 (phase 5) + bf16 (phase 1 next step)
    {
      const ushort_t* hbp = &h_w[w][lc*24 + (lq-2)*8];
      #pragma unroll
      for (int tt = 0; tt < 16; ++tt) {
        const ushort_t* rep = &re_s[w][tt*392 + lc*24 + lq*8];
        const ushort_t* ap = (lq < 2) ? rep : hbp;
        short8 a = *(const short8*)ap;
        floatx4 d = __builtin_amdgcn_mfma_f32_16x16x32_bf16(a, bfrag, cm[tt], 0, 0, 0);
        float pm = fmaxf(fmaxf(d[0], d[1]), fmaxf(d[2], d[3]));
        pm = fmaxf(pm, __shfl_xor(pm, 16, 64));
        pm = fmaxf(pm, __shfl_xor(pm, 32, 64));
        if (lq == (tt & 3)) {
          float cvv = fmaxf(pm, 0.0f);
          ctx_s[w][tt*16 + lc] = cvv;
          ctx_bf[w][tt*24 + lc] = f2bf1(cvv);
        }
      }
    }
    // phase 5: o4 = (h+ctx)@out_W + b; lane (lq,lc) owns (agent lc, output lq);
    // outputs + pos/prev advance (read by next step's phases 1/3, program order)
    {
      float acc = sb_o[lq];
      const floatx4* hp4 = (const floatx4*)&h_s[w][lc*16];
      const floatx4* cx4 = (const floatx4*)&ctx_s[w][lc*16];
      #pragma unroll
      for (int mm = 0; mm < 4; ++mm) {
        floatx4 hv = hp4[mm];
        floatx4 cv = cx4[mm];
        #pragma unroll
        for (int r = 0; r < 4; ++r)
          acc = fmaf(hv[r]+cv[r], sW_o[(mm*4+r)*4 + lq], acc);
      }
      float sc = __shfl_down(acc, 32, 64);   // lq<2 grabs o4[lq+2]
      if (lq < 2) {
        float mu = acc;
        float scale = fminf(fmaxf(sc, -9.0f), 4.0f);
        float sd = __expf(scale);
        float pr = fmaf(sd, nz, mu);
        int o = (t*B_ + s*N_ + lc)*2 + lq;
        out[o]          = pr;
        out[MU_OFF + o] = mu;
        out[SD_OFF + o] = sd;
        pos_s[w][lc*2+lq] += pr;
        prev_bf[w][lc*2+lq] = f2bf1(pr);
      }
    }
  }
  #undef LSTM_EW
  #undef LOAD_GATE_FRAG
}

extern "C" void kernel_launch(void* const* d_in, const int* in_sizes, int n_in,
                              void* d_out, int out_size, void* d_ws, size_t ws_size,
                              hipStream_t stream) {
  (void)in_sizes; (void)n_in; (void)d_ws; (void)ws_size; (void)out_size;
  traj_ar_kernel<<<dim3(S_/SCN_), dim3(128), 0, stream>>>(
      (const float*)d_in[0],  (const float*)d_in[1],  (const int*)d_in[2],   (const float*)d_in[3],
      (const float*)d_in[4],  (const float*)d_in[5],  (const float*)d_in[6], (const float*)d_in[7],
      (const float*)d_in[8],  (const float*)d_in[9],  (const float*)d_in[10],(const float*)d_in[11],
      (const float*)d_in[12], (const float*)d_in[13], (const float*)d_in[14],(const float*)d_in[15],
      (const float*)d_in[16], (const float*)d_in[17], (const float*)d_in[18],(const float*)d_in[19],
      (float*)d_out);
}